// Round 5
// baseline (3627.492 us; speedup 1.0000x reference)
//
#include <hip/hip_runtime.h>

// Seq2Seq LSTM (B=1024, T_IN=168, F_IN=8, H=256, T_OUT=96) on gfx950.
// Round 5: round-4 structure with the fc-exchange stride bug fixed.
//  - 256 blocks; group = blockIdx>>2 owns 16 batch rows; slice = blockIdx&3
//    owns h-units [slice*64, +64) -> 256 of 1024 gate columns.
//  - per wave: 2 N-frags x 9 K-frags = 18 MFMA, weights 100% VGPR-resident.
//  - per-step h exchange between the 4 blocks of a group through the MALL:
//    agent-scope relaxed atomics for data, release fetch_add + acquire spin
//    on a per-group counter, parity double-buffer (skew <= 1 step).
//  - A-tile in LDS, bank-group swizzle phys = row*512 + (off ^ ((row&7)<<4)).
//  - BUGFIX vs round 4: fcG stride was 512 floats but each group uses 1024
//    (2 parities x 512) -> neighbor groups clobbered each other's decoder
//    fc partials (absmax 0.149). Stride is now 1024.

typedef _Float16 f16x8 __attribute__((ext_vector_type(8)));
typedef float f32x4 __attribute__((ext_vector_type(4)));

#define NSTEPS 264
#define NENC   168

// ws offsets (bytes)
#define XF_OFF   0u
#define WPE_OFF  2752512u
#define WPD_OFF  3342336u
#define CTR_OFF  3932160u   // 64 * u32
#define HEX_OFF  3932416u   // [grp][parity][col 256][row 16] f16 = 64 * 16384 B
#define FC_OFF   4980992u   // [grp][parity][slice 4][wv 8][row 16] f32 = 64 * 4096 B

__device__ __forceinline__ float sigm(float x) {
    float e = __builtin_amdgcn_exp2f(-1.4426950408889634f * x);
    return __builtin_amdgcn_rcpf(1.0f + e);
}
__device__ __forceinline__ float tanh_f(float x) {
    float e = __builtin_amdgcn_exp2f(-2.8853900817779268f * x);
    return 2.0f * __builtin_amdgcn_rcpf(1.0f + e) - 1.0f;
}
__device__ __forceinline__ f32x4 mfma(f16x8 a, f16x8 b, f32x4 c) {
    return __builtin_amdgcn_mfma_f32_16x16x32_f16(a, b, c, 0, 0, 0);
}

// ---------- setup kernels ----------

// inputs (B,T,F) f32 -> xf16 [t][b][f] f16
__global__ void k_convert_x(const float* __restrict__ in, _Float16* __restrict__ xf16) {
    int idx = blockIdx.x * 256 + threadIdx.x;
    if (idx >= 168 * 1024 * 8) return;
    int f = idx & 7;
    int b = (idx >> 3) & 1023;
    int t = idx >> 13;
    xf16[idx] = (_Float16)in[(b * 168 + t) * 8 + f];
}

// pack weights fragment-linear for the 4-way split:
// flat = wvs*9216 + kt*1024 + nt*512 + lane*8 + j   (wvs = slice*8 + wv)
// n = (nt*2 + (p>>3))*256 + (wvs>>3)*64 + (wvs&7)*8 + (p&7), p = lane&15
// k = kt*32 + (lane>>4)*8 + j
__global__ void k_pack_w(const float* __restrict__ Whh, const float* __restrict__ Wih,
                         int IN, _Float16* __restrict__ Wp) {
    int idx = blockIdx.x * 256 + threadIdx.x;
    if (idx >= 294912) return;
    int j    = idx & 7;
    int lane = (idx >> 3) & 63;
    int nt   = (idx >> 9) & 1;
    int kt   = (idx >> 10) % 9;
    int wvs  = idx / 9216;
    int p = lane & 15;
    int n = (nt * 2 + (p >> 3)) * 256 + (wvs >> 3) * 64 + (wvs & 7) * 8 + (p & 7);
    int k = kt * 32 + (lane >> 4) * 8 + j;
    float v = 0.0f;
    if (k < 256)            v = Whh[n * 256 + k];
    else if (k - 256 < IN)  v = Wih[n * IN + (k - 256)];
    Wp[idx] = (_Float16)v;
}

// ---------- main persistent kernel ----------

__global__ __launch_bounds__(512, 2) void lstm4(
    const _Float16* __restrict__ xf16,
    const _Float16* __restrict__ WpE,
    const _Float16* __restrict__ WpD,
    const float* __restrict__ bihE, const float* __restrict__ bhhE,
    const float* __restrict__ bihD, const float* __restrict__ bhhD,
    const float* __restrict__ fcW, const float* __restrict__ fcb,
    char* __restrict__ hexH, float* __restrict__ hexFC,
    unsigned* __restrict__ ctrArr,
    float* __restrict__ out) {

    __shared__ _Float16 A[16 * 256];    // 8 KB, swizzled [row][hcol]
    __shared__ _Float16 xs[16][8];      // current x per batch row

    const int tid  = threadIdx.x;
    const int lane = tid & 63;
    const int wv   = tid >> 6;
    const int l15  = lane & 15;
    const int lg   = lane >> 4;
    const int grp   = blockIdx.x >> 2;
    const int slice = blockIdx.x & 3;
    const int b0    = grp * 16;

    char*     hexG = hexH + (size_t)grp * 16384;
    float*    fcG  = hexFC + grp * 1024;          // [parity][slice4][wv8][row16]
    unsigned* ctr  = ctrArr + grp;

    // ---- weights (encoder) fully in VGPRs ----
    f16x8 wr[9][2];
    const _Float16* wpe = WpE + (slice * 8 + wv) * 9216;
    const _Float16* wpd = WpD + (slice * 8 + wv) * 9216;
#pragma unroll
    for (int kt = 0; kt < 9; ++kt)
#pragma unroll
        for (int nt = 0; nt < 2; ++nt)
            wr[kt][nt] = *(const f16x8*)(wpe + (size_t)(kt * 2 + nt) * 512 + lane * 8);

    float bia[2];
#pragma unroll
    for (int nt = 0; nt < 2; ++nt) {
        int n = (nt * 2 + (l15 >> 3)) * 256 + slice * 64 + wv * 8 + (l15 & 7);
        bia[nt] = bihE[n] + bhhE[n];
    }
    const float fcwv = fcW[slice * 64 + wv * 8 + (l15 & 7)];
    const float fcbv = fcb[0];

    // constant A-frag read addrs (swizzled)
    int aaddr[8];
#pragma unroll
    for (int kt = 0; kt < 8; ++kt)
        aaddr[kt] = l15 * 512 + ((((kt * 4 + lg) ^ (l15 & 7)) & 31) << 4);

    // zero A (h0 = 0), load x0
    for (int i = tid; i < 16 * 256; i += 512) A[i] = (_Float16)0.0f;
    if (tid < 128) xs[tid >> 3][tid & 7] = xf16[(size_t)(b0 + (tid >> 3)) * 8 + (tid & 7)];

    float c_st[4] = {0.f, 0.f, 0.f, 0.f};

    // h-exchange store addr (lanes l15<8 active): [col][row] f16, col stride 32 B
    const int hcol = slice * 64 + wv * 8 + (l15 & 7);
    char* hdst0 = hexG + hcol * 32 + lg * 8;
    // fc store base: [slice][wv][row] floats
    float* fcdst0 = fcG + (slice * 8 + wv) * 16 + lg * 4;
    // reader: thread t loads 16B at t*16 -> col=t>>1, rows (t&1)*8..+8
    const int rcol = tid >> 1;
    const int rr0  = (tid & 1) * 8;

    __syncthreads();

#pragma unroll 1
    for (int it = 0; it < NSTEPS; ++it) {
        const bool enc = (it < NENC);
        // ---------- compute: gates for this slice ----------
        f32x4 acc[2];
        { f32x4 z = {0.f, 0.f, 0.f, 0.f}; acc[0] = z; acc[1] = z; }
        const char* Ab = (const char*)A;
#pragma unroll
        for (int kt = 0; kt < 8; ++kt) {
            f16x8 a = *(const f16x8*)(Ab + aaddr[kt]);
            acc[0] = mfma(a, wr[kt][0], acc[0]);
            acc[1] = mfma(a, wr[kt][1], acc[1]);
        }
        {
            f16x8 a = *(const f16x8*)&xs[l15][0];
            acc[0] = mfma(a, wr[8][0], acc[0]);
            acc[1] = mfma(a, wr[8][1], acc[1]);
        }
        // prefetch next x while MFMA latency drains
        _Float16 xreg = (_Float16)0.0f;
        if (enc && it < NENC - 1 && tid < 128)
            xreg = xf16[(size_t)((it + 1) * 1024 + b0 + (tid >> 3)) * 8 + (tid & 7)];

        const int par = (it + 1) & 1;
        // ---------- activation (4 units/lane; lane halves redundant) ----------
        union { unsigned short s[4]; unsigned long long q; } hq;
        float pv[4];
#pragma unroll
        for (int r = 0; r < 4; ++r) {
            float a0 = acc[0][r] + bia[0];
            float a1 = acc[1][r] + bia[1];
            float o0 = __shfl_xor(a0, 8);
            float o1 = __shfl_xor(a1, 8);
            bool lo = (l15 < 8);
            float iv = lo ? a0 : o0;
            float fv = lo ? o0 : a0;
            float gv = lo ? a1 : o1;
            float ov = lo ? o1 : a1;
            float cn = sigm(fv) * c_st[r] + sigm(iv) * tanh_f(gv);
            c_st[r] = cn;
            float hn = sigm(ov) * tanh_f(cn);
            hq.s[r] = __builtin_bit_cast(unsigned short, (_Float16)hn);
            pv[r] = hn * fcwv;
        }
        // h slice -> exchange (4 consecutive rows packed as u64)
        if (l15 < 8)
            __hip_atomic_store((unsigned long long*)(hdst0 + par * 8192), hq.q,
                               __ATOMIC_RELAXED, __HIP_MEMORY_SCOPE_AGENT);
        if (!enc) {
            // per-wave fc partial: sum over the 8-lane u-group
#pragma unroll
            for (int r = 0; r < 4; ++r) {
                pv[r] += __shfl_xor(pv[r], 1);
                pv[r] += __shfl_xor(pv[r], 2);
                pv[r] += __shfl_xor(pv[r], 4);
            }
            if (l15 == 0) {
#pragma unroll
                for (int r = 0; r < 4; ++r)
                    __hip_atomic_store((unsigned*)(fcdst0 + par * 512 + r),
                                       __builtin_bit_cast(unsigned, pv[r]),
                                       __ATOMIC_RELAXED, __HIP_MEMORY_SCOPE_AGENT);
            }
        }
        __syncthreads();   // drains all exchange stores (vmcnt) + A reads done
        if (tid == 0)
            __hip_atomic_fetch_add(ctr, 1u, __ATOMIC_RELEASE, __HIP_MEMORY_SCOPE_AGENT);
        if (it == NSTEPS - 1) break;
        if (tid == 0) {
            const unsigned tgt = 4u * (unsigned)(it + 1);
            while (__hip_atomic_load(ctr, __ATOMIC_ACQUIRE, __HIP_MEMORY_SCOPE_AGENT) < tgt) {}
        }
        __syncthreads();   // exchange ready for all threads

        // ---------- rebuild A from all 4 slices ----------
        {
            const char* src = hexG + par * 8192 + tid * 16;
            unsigned long long q0 = __hip_atomic_load((const unsigned long long*)src,
                                                      __ATOMIC_RELAXED, __HIP_MEMORY_SCOPE_AGENT);
            unsigned long long q1 = __hip_atomic_load((const unsigned long long*)(src + 8),
                                                      __ATOMIC_RELAXED, __HIP_MEMORY_SCOPE_AGENT);
            union { unsigned long long q[2]; unsigned short s[8]; } u;
            u.q[0] = q0; u.q[1] = q1;
            char* Aw = (char*)A;
#pragma unroll
            for (int j = 0; j < 8; ++j) {   // rows rr0+j, (rr0+j)&7 == j
                *(unsigned short*)(Aw + (rr0 + j) * 512 + ((rcol * 2) ^ (j << 4))) = u.s[j];
            }
        }
        // ---------- xs update ----------
        if (enc) {
            if (it < NENC - 1) {
                if (tid < 128) xs[tid >> 3][tid & 7] = xreg;
            } else {
                // decoder x0: keep feat0 (= x167 feat0), zero feats 1..7
                if (tid < 128 && (tid & 7) != 0) xs[tid >> 3][tid & 7] = (_Float16)0.0f;
            }
        } else {
            if (tid < 16) {
                float pr = fcbv;
                const float* fp = fcG + par * 512;
#pragma unroll
                for (int sw = 0; sw < 32; ++sw)
                    pr += __builtin_bit_cast(float,
                        __hip_atomic_load((const unsigned*)(fp + sw * 16 + tid),
                                          __ATOMIC_RELAXED, __HIP_MEMORY_SCOPE_AGENT));
                xs[tid][0] = (_Float16)pr;
                if (slice == 0) out[(size_t)(b0 + tid) * 96 + (it - NENC)] = pr;
            }
        }
        // ---------- phase switch to decoder weights ----------
        if (it == NENC - 1) {
#pragma unroll
            for (int kt = 0; kt < 9; ++kt)
#pragma unroll
                for (int nt = 0; nt < 2; ++nt)
                    wr[kt][nt] = *(const f16x8*)(wpd + (size_t)(kt * 2 + nt) * 512 + lane * 8);
#pragma unroll
            for (int nt = 0; nt < 2; ++nt) {
                int n = (nt * 2 + (l15 >> 3)) * 256 + slice * 64 + wv * 8 + (l15 & 7);
                bia[nt] = bihD[n] + bhhD[n];
            }
        }
        __syncthreads();   // A + xs ready for next step
    }

    // ---------- tail: prediction of the last decoder step ----------
    if (tid == 0) {
        while (__hip_atomic_load(ctr, __ATOMIC_ACQUIRE, __HIP_MEMORY_SCOPE_AGENT)
               < 4u * (unsigned)NSTEPS) {}
    }
    __syncthreads();
    if (slice == 0 && tid < 16) {
        float pr = fcbv;
        const float* fp = fcG + ((NSTEPS) & 1) * 512;   // parity of last step = 0
#pragma unroll
        for (int sw = 0; sw < 32; ++sw)
            pr += __builtin_bit_cast(float,
                __hip_atomic_load((const unsigned*)(fp + sw * 16 + tid),
                                  __ATOMIC_RELAXED, __HIP_MEMORY_SCOPE_AGENT));
        out[(size_t)(b0 + tid) * 96 + 95] = pr;
    }
}

// ---------- launch ----------

extern "C" void kernel_launch(void* const* d_in, const int* in_sizes, int n_in,
                              void* d_out, int out_size, void* d_ws, size_t ws_size,
                              hipStream_t stream) {
    const float* inputs  = (const float*)d_in[0];
    const float* enc_Wih = (const float*)d_in[1];
    const float* enc_Whh = (const float*)d_in[2];
    const float* enc_bih = (const float*)d_in[3];
    const float* enc_bhh = (const float*)d_in[4];
    const float* dec_Wih = (const float*)d_in[5];
    const float* dec_Whh = (const float*)d_in[6];
    const float* dec_bih = (const float*)d_in[7];
    const float* dec_bhh = (const float*)d_in[8];
    const float* fc_W    = (const float*)d_in[9];
    const float* fc_b    = (const float*)d_in[10];

    char* ws = (char*)d_ws;
    _Float16* xf16 = (_Float16*)(ws + XF_OFF);
    _Float16* WpE  = (_Float16*)(ws + WPE_OFF);
    _Float16* WpD  = (_Float16*)(ws + WPD_OFF);
    unsigned* ctr  = (unsigned*)(ws + CTR_OFF);
    char*     hexH = ws + HEX_OFF;
    float*    hexFC= (float*)(ws + FC_OFF);

    // reset the group counters every launch (graph-capturable)
    hipMemsetAsync(ctr, 0, 64 * sizeof(unsigned), stream);

    k_convert_x<<<dim3(5376), dim3(256), 0, stream>>>(inputs, xf16);
    k_pack_w<<<dim3(1152), dim3(256), 0, stream>>>(enc_Whh, enc_Wih, 8, WpE);
    k_pack_w<<<dim3(1152), dim3(256), 0, stream>>>(dec_Whh, dec_Wih, 1, WpD);

    lstm4<<<dim3(256), dim3(512), 0, stream>>>(
        xf16, WpE, WpD, enc_bih, enc_bhh, dec_bih, dec_bhh, fc_W, fc_b,
        hexH, hexFC, ctr, (float*)d_out);
}

// Round 6
// 2449.622 us; speedup vs baseline: 1.4808x; 1.4808x over previous
//
#include <hip/hip_runtime.h>

// Seq2Seq LSTM (B=1024, T_IN=168, F_IN=8, H=256, T_OUT=96) on gfx950.
// Round 6: back to self-contained 64-block design (r5 proved per-step
// cross-block sync costs ~13us/step via MALL). Structural trims vs r3:
//  - A tile double-buffered (2x8KB) -> ONE __syncthreads per step.
//  - decoder x-term is rank-1 (dec_Wih is [1024x1]): folded into acc init
//    as bia[nt] + wih[n]*pred, pred computed per-lane from LDS partials.
//    No xs feedback, no kt8 MFMA, no extra decoder barriers.
//  - encoder kt8 weights streamed as 2KB/wave broadcast loads (L1-hot),
//    A-operand lane-masked; frees 16KB LDS so kt6-7 stay LDS-resident.
//  - weights: kt0-4 VGPR (40 frags), kt5 streamed (64KB/CU/step, L2-hot),
//    kt6-7 LDS (128KB).
// 64 blocks x 512 threads; wave wv owns h-units [wv*32, +32).

typedef _Float16 f16x8 __attribute__((ext_vector_type(8)));
typedef float f32x4 __attribute__((ext_vector_type(4)));

#define WPW  36864
#define NENC 168
#define NTOT 264

__device__ __forceinline__ float sigm(float x) {
    float e = __builtin_amdgcn_exp2f(-1.4426950408889634f * x);
    return __builtin_amdgcn_rcpf(1.0f + e);
}
__device__ __forceinline__ float tanh_f(float x) {
    float e = __builtin_amdgcn_exp2f(-2.8853900817779268f * x);
    return 2.0f * __builtin_amdgcn_rcpf(1.0f + e) - 1.0f;
}
__device__ __forceinline__ f32x4 mfma(f16x8 a, f16x8 b, f32x4 c) {
    return __builtin_amdgcn_mfma_f32_16x16x32_f16(a, b, c, 0, 0, 0);
}
__device__ __forceinline__ void mfma8(f32x4 acc[8], f16x8 a, const f16x8 b[8]) {
#pragma unroll
    for (int nt = 0; nt < 8; ++nt) acc[nt] = mfma(a, b[nt], acc[nt]);
}

// ---------- setup kernels (same packing as r3) ----------

__global__ void k_convert_x(const float* __restrict__ in, _Float16* __restrict__ xf16) {
    int idx = blockIdx.x * 256 + threadIdx.x;     // (t*1024+b)*8+f
    if (idx >= 168 * 1024 * 8) return;
    int f = idx & 7;
    int b = (idx >> 3) & 1023;
    int t = idx >> 13;
    xf16[idx] = (_Float16)in[(b * 168 + t) * 8 + f];
}

__global__ void k_pack_w(const float* __restrict__ Whh, const float* __restrict__ Wih,
                         int IN, _Float16* __restrict__ Wp) {
    int idx = blockIdx.x * 256 + threadIdx.x;
    if (idx >= 294912) return;
    int j    = idx & 7;
    int lane = (idx >> 3) & 63;
    int nt   = (idx >> 9) & 7;
    int kt   = (idx >> 12) % 9;
    int wv   = idx / 36864;
    int n = (nt >> 1) * 256 + wv * 32 + (nt & 1) * 16 + (lane & 15);
    int k = kt * 32 + (lane >> 4) * 8 + j;
    float v = 0.0f;
    if (k < 256)            v = Whh[n * 256 + k];
    else if (k - 256 < IN)  v = Wih[n * IN + (k - 256)];
    Wp[idx] = (_Float16)v;
}

// ---------- main persistent kernel ----------

__global__ __launch_bounds__(512, 2) void lstm6(
    const float* __restrict__ in0,
    const _Float16* __restrict__ xf16,
    const _Float16* __restrict__ WpE,
    const _Float16* __restrict__ WpD,
    const float* __restrict__ bihE, const float* __restrict__ bhhE,
    const float* __restrict__ bihD, const float* __restrict__ bhhD,
    const float* __restrict__ fcW, const float* __restrict__ fcb,
    float* __restrict__ out) {

    __shared__ f16x8 Blds[8][16][64];       // 128 KB: kt6,7 per wave (wave-local)
    __shared__ _Float16 A[2][16 * 256];     //  16 KB: h tile, double-buffered, swizzled
    __shared__ f16x8 xs[2][16];             // 512 B : x staging, double-buffered
    __shared__ f32x4 partial[2][16][2];     //   1 KB: decoder fc partials, dbuf

    const int tid  = threadIdx.x;
    const int lane = tid & 63;
    const int wv   = tid >> 6;
    const int l15  = lane & 15;
    const int lg   = lane >> 4;
    const int b0   = blockIdx.x * 16;

    const _Float16* wpe = WpE + wv * WPW;
    const _Float16* wpd = WpD + wv * WPW;
    const _Float16* wp8 = wpe + 64 * 512;   // encoder kt8 base

    // encoder weights: kt0-4 -> VGPR, kt6-7 -> LDS (own wave slice)
    f16x8 wr[5][8];
#pragma unroll
    for (int kt = 0; kt < 5; ++kt)
#pragma unroll
        for (int nt = 0; nt < 8; ++nt)
            wr[kt][nt] = *(const f16x8*)(wpe + (size_t)(kt * 8 + nt) * 512 + lane * 8);
#pragma unroll
    for (int kt = 6; kt < 8; ++kt)
#pragma unroll
        for (int nt = 0; nt < 8; ++nt)
            Blds[wv][(kt - 6) * 8 + nt][lane] = *(const f16x8*)(wpe + (size_t)(kt * 8 + nt) * 512 + lane * 8);

    float bia[8];
#pragma unroll
    for (int nt = 0; nt < 8; ++nt) {
        int n = (nt >> 1) * 256 + wv * 32 + (nt & 1) * 16 + l15;
        bia[nt] = bihE[n] + bhhE[n];
    }
    const float fcw0 = fcW[wv * 32 + l15];
    const float fcw1 = fcW[wv * 32 + 16 + l15];
    const float fcbv = fcb[0];

    // swizzled A-frag read offsets (kt 0..7)
    int aaddr[8];
#pragma unroll
    for (int kt = 0; kt < 8; ++kt)
        aaddr[kt] = l15 * 512 + ((((kt * 4 + lg) ^ (l15 & 7)) & 31) << 4);

    // zero A[0] (h0 = 0; A[1] fully overwritten at it=0), load x0
    for (int i = tid; i < 16 * 256; i += 512) A[0][i] = (_Float16)0.0f;
    if (tid < 128)
        ((_Float16*)&xs[0][tid >> 3])[tid & 7] = xf16[(size_t)(b0 + (tid >> 3)) * 8 + (tid & 7)];

    float c_st[2][4] = {{0.f,0.f,0.f,0.f},{0.f,0.f,0.f,0.f}};
    float wih_s[8] = {0,0,0,0,0,0,0,0};
    float pred[4]  = {0,0,0,0};

    __syncthreads();

#pragma unroll 1
    for (int it = 0; it < NTOT; ++it) {
        const bool enc = (it < NENC);
        const int rb = it & 1, wbuf = rb ^ 1;
        const char* ab = (const char*)&A[0][0] + rb * 8192;
        char*       aw = (char*)&A[0][0] + wbuf * 8192;
        const _Float16* wp = enc ? wpe : wpd;

        // ---------- phase switch (once): decoder weights, rank-1 wih, pred0 ----------
        if (it == NENC) {
#pragma unroll
            for (int kt = 0; kt < 5; ++kt)
#pragma unroll
                for (int nt = 0; nt < 8; ++nt)
                    wr[kt][nt] = *(const f16x8*)(wpd + (size_t)(kt * 8 + nt) * 512 + lane * 8);
#pragma unroll
            for (int kt = 6; kt < 8; ++kt)
#pragma unroll
                for (int nt = 0; nt < 8; ++nt)
                    Blds[wv][(kt - 6) * 8 + nt][lane] = *(const f16x8*)(wpd + (size_t)(kt * 8 + nt) * 512 + lane * 8);
            // (wave-local slice: no barrier needed; compiler orders ds_write->ds_read)
#pragma unroll
            for (int nt = 0; nt < 8; ++nt) {
                int n = (nt >> 1) * 256 + wv * 32 + (nt & 1) * 16 + l15;
                bia[nt]   = bihD[n] + bhhD[n];
                wih_s[nt] = ((const float*)bihD == nullptr) ? 0.f : 0.f; // placeholder, set below
            }
            // decoder input weight column (dec_Wih is [1024][1])
#pragma unroll
            for (int nt = 0; nt < 8; ++nt) {
                int n = (nt >> 1) * 256 + wv * 32 + (nt & 1) * 16 + l15;
                wih_s[nt] = fcb == nullptr ? 0.f : 0.f; // overwritten immediately below
            }
            // NOTE: real loads (kept separate to avoid clutter above)
#pragma unroll
            for (int nt = 0; nt < 8; ++nt) {
                int n = (nt >> 1) * 256 + wv * 32 + (nt & 1) * 16 + l15;
                wih_s[nt] = __ldg(&bhhD[0]) * 0.f; // dummy to keep shape; replaced:
            }
            // --- actual wih load (dec_Wih passed via fcW? no: see launch args) ---
            // (the launcher passes dec_Wih as dWih below)
            ;
#pragma unroll
            for (int r = 0; r < 4; ++r)
                pred[r] = in0[((size_t)(b0 + lg * 4 + r) * 168 + 167) * 8 + 0];
        }

        // ---------- acc init ----------
        f32x4 acc[8];
        if (enc) {
#pragma unroll
            for (int nt = 0; nt < 8; ++nt) { f32x4 v = {bia[nt], bia[nt], bia[nt], bia[nt]}; acc[nt] = v; }
        } else {
            if (it > NENC) {
#pragma unroll
                for (int r = 0; r < 4; ++r) {
                    const int row = lg * 4 + r;
                    f32x4 pa = partial[rb][row][0];
                    f32x4 pb = partial[rb][row][1];
                    pred[r] = fcbv + (((pa[0] + pa[1]) + (pa[2] + pa[3]))
                                    + ((pb[0] + pb[1]) + (pb[2] + pb[3])));
                    if (wv == 0 && l15 == 0)
                        out[(size_t)(b0 + row) * 96 + (it - NENC - 1)] = pred[r];
                }
            }
#pragma unroll
            for (int nt = 0; nt < 8; ++nt) {
                f32x4 v;
#pragma unroll
                for (int r = 0; r < 4; ++r) v[r] = __builtin_fmaf(wih_s[nt], pred[r], bia[nt]);
                acc[nt] = v;
            }
        }

        // ---------- GEMM ----------
        f16x8 s5[8];
#pragma unroll
        for (int nt = 0; nt < 8; ++nt)
            s5[nt] = *(const f16x8*)(wp + (size_t)(5 * 8 + nt) * 512 + lane * 8);

        _Float16 xreg = (_Float16)0.0f;
        if (enc && it < NENC - 1 && tid < 128)
            xreg = xf16[(size_t)((it + 1) * 1024 + b0 + (tid >> 3)) * 8 + (tid & 7)];

#pragma unroll
        for (int kt = 0; kt < 5; ++kt) {
            f16x8 a = *(const f16x8*)(ab + aaddr[kt]);
            mfma8(acc, a, wr[kt]);
        }
        {
            f16x8 a = *(const f16x8*)(ab + aaddr[5]);
            mfma8(acc, a, s5);
        }
        __builtin_amdgcn_sched_barrier(0);
        f16x8 k8b[8];
        if (enc) {
#pragma unroll
            for (int nt = 0; nt < 8; ++nt)
                k8b[nt] = *(const f16x8*)(wp8 + (size_t)nt * 512 + l15 * 8);
        }
#pragma unroll
        for (int kt = 6; kt < 8; ++kt) {
            f16x8 a = *(const f16x8*)(ab + aaddr[kt]);
#pragma unroll
            for (int nt = 0; nt < 8; ++nt)
                acc[nt] = mfma(a, Blds[wv][(kt - 6) * 8 + nt][lane], acc[nt]);
        }
        if (enc) {
            f16x8 a8 = xs[rb][l15];
            _Float16 m = (_Float16)(lg == 0 ? 1.0f : 0.0f);
            a8 = a8 * m;               // zero A-operand on lanes whose k-range has no features
            mfma8(acc, a8, k8b);
        }

        // ---------- activation + h write (swizzled) ----------
        float hnv[2][4];
#pragma unroll
        for (int half = 0; half < 2; ++half) {
#pragma unroll
            for (int r = 0; r < 4; ++r) {
                float iv = acc[0 + half][r];
                float fv = acc[2 + half][r];
                float gv = acc[4 + half][r];
                float ov = acc[6 + half][r];
                float cn = sigm(fv) * c_st[half][r] + sigm(iv) * tanh_f(gv);
                c_st[half][r] = cn;
                float hn = sigm(ov) * tanh_f(cn);
                hnv[half][r] = hn;
                int row  = lg * 4 + r;
                int colb = (wv * 32 + half * 16 + l15) * 2;
                *(_Float16*)(aw + row * 512 + (colb ^ ((row & 7) << 4))) = (_Float16)hn;
            }
        }

        if (!enc) {
            // fc partials for the NEXT step's pred
#pragma unroll
            for (int r = 0; r < 4; ++r) {
                float pv = hnv[0][r] * fcw0 + hnv[1][r] * fcw1;
                pv += __shfl_xor(pv, 1);
                pv += __shfl_xor(pv, 2);
                pv += __shfl_xor(pv, 4);
                pv += __shfl_xor(pv, 8);
                if (l15 == 0)
                    ((float*)&partial[wbuf][lg * 4 + r][0])[wv] = pv;
            }
        } else if (it < NENC - 1) {
            if (tid < 128)
                ((_Float16*)&xs[wbuf][tid >> 3])[tid & 7] = xreg;
        }

        __syncthreads();   // the ONLY per-step barrier
    }

    // ---------- tail: last prediction (partials of it=263 are in parity 0) ----------
    if (wv == 0 && l15 == 0) {
#pragma unroll
        for (int r = 0; r < 4; ++r) {
            const int row = lg * 4 + r;
            f32x4 pa = partial[0][row][0];
            f32x4 pb = partial[0][row][1];
            float pr = fcbv + (((pa[0] + pa[1]) + (pa[2] + pa[3]))
                             + ((pb[0] + pb[1]) + (pb[2] + pb[3])));
            out[(size_t)(b0 + row) * 96 + 95] = pr;
        }
    }
}

// wrapper kernel arg for dec_Wih (separate to keep lstm6 signature clean)
__global__ __launch_bounds__(512, 2) void lstm6_full(
    const float* __restrict__ in0,
    const _Float16* __restrict__ xf16,
    const _Float16* __restrict__ WpE,
    const _Float16* __restrict__ WpD,
    const float* __restrict__ bihE, const float* __restrict__ bhhE,
    const float* __restrict__ bihD, const float* __restrict__ bhhD,
    const float* __restrict__ dWih,
    const float* __restrict__ fcW, const float* __restrict__ fcb,
    float* __restrict__ out);

// ---------- launch ----------

extern "C" void kernel_launch(void* const* d_in, const int* in_sizes, int n_in,
                              void* d_out, int out_size, void* d_ws, size_t ws_size,
                              hipStream_t stream) {
    const float* inputs  = (const float*)d_in[0];
    const float* enc_Wih = (const float*)d_in[1];
    const float* enc_Whh = (const float*)d_in[2];
    const float* enc_bih = (const float*)d_in[3];
    const float* enc_bhh = (const float*)d_in[4];
    const float* dec_Wih = (const float*)d_in[5];
    const float* dec_Whh = (const float*)d_in[6];
    const float* dec_bih = (const float*)d_in[7];
    const float* dec_bhh = (const float*)d_in[8];
    const float* fc_W    = (const float*)d_in[9];
    const float* fc_b    = (const float*)d_in[10];

    char* ws = (char*)d_ws;
    _Float16* xf16 = (_Float16*)(ws);
    _Float16* WpE  = (_Float16*)(ws + 2752512);
    _Float16* WpD  = (_Float16*)(ws + 2752512 + 589824);

    k_convert_x<<<dim3(5376), dim3(256), 0, stream>>>(inputs, xf16);
    k_pack_w<<<dim3(1152), dim3(256), 0, stream>>>(enc_Whh, enc_Wih, 8, WpE);
    k_pack_w<<<dim3(1152), dim3(256), 0, stream>>>(dec_Whh, dec_Wih, 1, WpD);

    lstm6_full<<<dim3(64), dim3(512), 0, stream>>>(
        inputs, xf16, WpE, WpD, enc_bih, enc_bhh, dec_bih, dec_bhh,
        dec_Wih, fc_W, fc_b, (float*)d_out);
}

// ---------- the real kernel (with dWih) ----------

__global__ __launch_bounds__(512, 2) void lstm6_full(
    const float* __restrict__ in0,
    const _Float16* __restrict__ xf16,
    const _Float16* __restrict__ WpE,
    const _Float16* __restrict__ WpD,
    const float* __restrict__ bihE, const float* __restrict__ bhhE,
    const float* __restrict__ bihD, const float* __restrict__ bhhD,
    const float* __restrict__ dWih,
    const float* __restrict__ fcW, const float* __restrict__ fcb,
    float* __restrict__ out) {

    __shared__ f16x8 Blds[8][16][64];
    __shared__ _Float16 A[2][16 * 256];
    __shared__ f16x8 xs[2][16];
    __shared__ f32x4 partial[2][16][2];

    const int tid  = threadIdx.x;
    const int lane = tid & 63;
    const int wv   = tid >> 6;
    const int l15  = lane & 15;
    const int lg   = lane >> 4;
    const int b0   = blockIdx.x * 16;

    const _Float16* wpe = WpE + wv * WPW;
    const _Float16* wpd = WpD + wv * WPW;
    const _Float16* wp8 = wpe + 64 * 512;

    f16x8 wr[5][8];
#pragma unroll
    for (int kt = 0; kt < 5; ++kt)
#pragma unroll
        for (int nt = 0; nt < 8; ++nt)
            wr[kt][nt] = *(const f16x8*)(wpe + (size_t)(kt * 8 + nt) * 512 + lane * 8);
#pragma unroll
    for (int kt = 6; kt < 8; ++kt)
#pragma unroll
        for (int nt = 0; nt < 8; ++nt)
            Blds[wv][(kt - 6) * 8 + nt][lane] = *(const f16x8*)(wpe + (size_t)(kt * 8 + nt) * 512 + lane * 8);

    float bia[8];
#pragma unroll
    for (int nt = 0; nt < 8; ++nt) {
        int n = (nt >> 1) * 256 + wv * 32 + (nt & 1) * 16 + l15;
        bia[nt] = bihE[n] + bhhE[n];
    }
    const float fcw0 = fcW[wv * 32 + l15];
    const float fcw1 = fcW[wv * 32 + 16 + l15];
    const float fcbv = fcb[0];

    int aaddr[8];
#pragma unroll
    for (int kt = 0; kt < 8; ++kt)
        aaddr[kt] = l15 * 512 + ((((kt * 4 + lg) ^ (l15 & 7)) & 31) << 4);

    for (int i = tid; i < 16 * 256; i += 512) A[0][i] = (_Float16)0.0f;
    if (tid < 128)
        ((_Float16*)&xs[0][tid >> 3])[tid & 7] = xf16[(size_t)(b0 + (tid >> 3)) * 8 + (tid & 7)];

    float c_st[2][4] = {{0.f,0.f,0.f,0.f},{0.f,0.f,0.f,0.f}};
    float wih_s[8] = {0,0,0,0,0,0,0,0};
    float pred[4]  = {0,0,0,0};

    __syncthreads();

#pragma unroll 1
    for (int it = 0; it < NTOT; ++it) {
        const bool enc = (it < NENC);
        const int rb = it & 1, wbuf = rb ^ 1;
        const char* ab = (const char*)&A[0][0] + rb * 8192;
        char*       aw = (char*)&A[0][0] + wbuf * 8192;
        const _Float16* wp = enc ? wpe : wpd;

        if (it == NENC) {
#pragma unroll
            for (int kt = 0; kt < 5; ++kt)
#pragma unroll
                for (int nt = 0; nt < 8; ++nt)
                    wr[kt][nt] = *(const f16x8*)(wpd + (size_t)(kt * 8 + nt) * 512 + lane * 8);
#pragma unroll
            for (int kt = 6; kt < 8; ++kt)
#pragma unroll
                for (int nt = 0; nt < 8; ++nt)
                    Blds[wv][(kt - 6) * 8 + nt][lane] = *(const f16x8*)(wpd + (size_t)(kt * 8 + nt) * 512 + lane * 8);
#pragma unroll
            for (int nt = 0; nt < 8; ++nt) {
                int n = (nt >> 1) * 256 + wv * 32 + (nt & 1) * 16 + l15;
                bia[nt]   = bihD[n] + bhhD[n];
                wih_s[nt] = dWih[n];
            }
#pragma unroll
            for (int r = 0; r < 4; ++r)
                pred[r] = in0[((size_t)(b0 + lg * 4 + r) * 168 + 167) * 8 + 0];
        }

        f32x4 acc[8];
        if (enc) {
#pragma unroll
            for (int nt = 0; nt < 8; ++nt) { f32x4 v = {bia[nt], bia[nt], bia[nt], bia[nt]}; acc[nt] = v; }
        } else {
            if (it > NENC) {
#pragma unroll
                for (int r = 0; r < 4; ++r) {
                    const int row = lg * 4 + r;
                    f32x4 pa = partial[rb][row][0];
                    f32x4 pb = partial[rb][row][1];
                    pred[r] = fcbv + (((pa[0] + pa[1]) + (pa[2] + pa[3]))
                                    + ((pb[0] + pb[1]) + (pb[2] + pb[3])));
                    if (wv == 0 && l15 == 0)
                        out[(size_t)(b0 + row) * 96 + (it - NENC - 1)] = pred[r];
                }
            }
#pragma unroll
            for (int nt = 0; nt < 8; ++nt) {
                f32x4 v;
#pragma unroll
                for (int r = 0; r < 4; ++r) v[r] = __builtin_fmaf(wih_s[nt], pred[r], bia[nt]);
                acc[nt] = v;
            }
        }

        f16x8 s5[8];
#pragma unroll
        for (int nt = 0; nt < 8; ++nt)
            s5[nt] = *(const f16x8*)(wp + (size_t)(5 * 8 + nt) * 512 + lane * 8);

        _Float16 xreg = (_Float16)0.0f;
        if (enc && it < NENC - 1 && tid < 128)
            xreg = xf16[(size_t)((it + 1) * 1024 + b0 + (tid >> 3)) * 8 + (tid & 7)];

#pragma unroll
        for (int kt = 0; kt < 5; ++kt) {
            f16x8 a = *(const f16x8*)(ab + aaddr[kt]);
            mfma8(acc, a, wr[kt]);
        }
        {
            f16x8 a = *(const f16x8*)(ab + aaddr[5]);
            mfma8(acc, a, s5);
        }
        __builtin_amdgcn_sched_barrier(0);
        f16x8 k8b[8];
        if (enc) {
#pragma unroll
            for (int nt = 0; nt < 8; ++nt)
                k8b[nt] = *(const f16x8*)(wp8 + (size_t)nt * 512 + l15 * 8);
        }
#pragma unroll
        for (int kt = 6; kt < 8; ++kt) {
            f16x8 a = *(const f16x8*)(ab + aaddr[kt]);
#pragma unroll
            for (int nt = 0; nt < 8; ++nt)
                acc[nt] = mfma(a, Blds[wv][(kt - 6) * 8 + nt][lane], acc[nt]);
        }
        if (enc) {
            f16x8 a8 = xs[rb][l15];
            _Float16 m = (_Float16)(lg == 0 ? 1.0f : 0.0f);
            a8 = a8 * m;
            mfma8(acc, a8, k8b);
        }

        float hnv[2][4];
#pragma unroll
        for (int half = 0; half < 2; ++half) {
#pragma unroll
            for (int r = 0; r < 4; ++r) {
                float iv = acc[0 + half][r];
                float fv = acc[2 + half][r];
                float gv = acc[4 + half][r];
                float ov = acc[6 + half][r];
                float cn = sigm(fv) * c_st[half][r] + sigm(iv) * tanh_f(gv);
                c_st[half][r] = cn;
                float hn = sigm(ov) * tanh_f(cn);
                hnv[half][r] = hn;
                int row  = lg * 4 + r;
                int colb = (wv * 32 + half * 16 + l15) * 2;
                *(_Float16*)(aw + row * 512 + (colb ^ ((row & 7) << 4))) = (_Float16)hn;
            }
        }

        if (!enc) {
#pragma unroll
            for (int r = 0; r < 4; ++r) {
                float pv = hnv[0][r] * fcw0 + hnv[1][r] * fcw1;
                pv += __shfl_xor(pv, 1);
                pv += __shfl_xor(pv, 2);
                pv += __shfl_xor(pv, 4);
                pv += __shfl_xor(pv, 8);
                if (l15 == 0)
                    ((float*)&partial[wbuf][lg * 4 + r][0])[wv] = pv;
            }
        } else if (it < NENC - 1) {
            if (tid < 128)
                ((_Float16*)&xs[wbuf][tid >> 3])[tid & 7] = xreg;
        }

        __syncthreads();
    }

    if (wv == 0 && l15 == 0) {
#pragma unroll
        for (int r = 0; r < 4; ++r) {
            const int row = lg * 4 + r;
            f32x4 pa = partial[0][row][0];
            f32x4 pb = partial[0][row][1];
            float pr = fcbv + (((pa[0] + pa[1]) + (pa[2] + pa[3]))
                             + ((pb[0] + pb[1]) + (pb[2] + pb[3])));
            out[(size_t)(b0 + row) * 96 + 95] = pr;
        }
    }
}

// Round 7
// 1813.913 us; speedup vs baseline: 1.9998x; 1.3505x over previous
//
#include <hip/hip_runtime.h>

// Seq2Seq LSTM (B=1024, T_IN=168, F_IN=8, H=256, T_OUT=96) on gfx950.
// Round 7: r3's proven two-loop structure + three minimal structural deltas:
//  (1) A tile double-buffered -> ONE __syncthreads per step (r3 had 2+).
//  (2) decoder x-term rank-1 fold (dec_Wih is [1024x1]): acc init =
//      fma(wih[n], pred, bias); pred recomputed per-lane from LDS partials.
//      No xs feedback MFMA, no serial tid<16 section, no extra barriers.
//  (3) encoder kt8 weights VGPR-resident as a 6th reg-kt. The packed kt8
//      B-fragment is already 0 for lanes lg>0 (k>=264), so A-operand =
//      xs[l15] on all lanes is exact without masking. No per-step k8 loads.
// Weights: kt0-4,kt8 VGPR (96 regs) | kt5 streamed from L2 | kt6,7 LDS.
// Two separate loops (encoder/decoder) to keep live ranges small — r6's
// unified branchy loop spilled (WRITE_SIZE 144MB); this must show ~25MB.

typedef _Float16 f16x8 __attribute__((ext_vector_type(8)));
typedef float f32x4 __attribute__((ext_vector_type(4)));

#define WPW  36864
#define NENC 168
#define NDEC 96

__device__ __forceinline__ float sigm(float x) {
    float e = __builtin_amdgcn_exp2f(-1.4426950408889634f * x);
    return __builtin_amdgcn_rcpf(1.0f + e);
}
__device__ __forceinline__ float tanh_f(float x) {
    float e = __builtin_amdgcn_exp2f(-2.8853900817779268f * x);
    return 2.0f * __builtin_amdgcn_rcpf(1.0f + e) - 1.0f;
}
__device__ __forceinline__ f32x4 mfma(f16x8 a, f16x8 b, f32x4 c) {
    return __builtin_amdgcn_mfma_f32_16x16x32_f16(a, b, c, 0, 0, 0);
}
__device__ __forceinline__ void mfma8(f32x4 acc[8], f16x8 a, const f16x8 b[8]) {
#pragma unroll
    for (int nt = 0; nt < 8; ++nt) acc[nt] = mfma(a, b[nt], acc[nt]);
}

// ---------- setup kernels (unchanged from r3) ----------

__global__ void k_convert_x(const float* __restrict__ in, _Float16* __restrict__ xf16) {
    int idx = blockIdx.x * 256 + threadIdx.x;     // (t*1024+b)*8+f
    if (idx >= 168 * 1024 * 8) return;
    int f = idx & 7;
    int b = (idx >> 3) & 1023;
    int t = idx >> 13;
    xf16[idx] = (_Float16)in[(b * 168 + t) * 8 + f];
}

__global__ void k_pack_w(const float* __restrict__ Whh, const float* __restrict__ Wih,
                         int IN, _Float16* __restrict__ Wp) {
    int idx = blockIdx.x * 256 + threadIdx.x;
    if (idx >= 294912) return;
    int j    = idx & 7;
    int lane = (idx >> 3) & 63;
    int nt   = (idx >> 9) & 7;
    int kt   = (idx >> 12) % 9;
    int wv   = idx / 36864;
    int n = (nt >> 1) * 256 + wv * 32 + (nt & 1) * 16 + (lane & 15);
    int k = kt * 32 + (lane >> 4) * 8 + j;
    float v = 0.0f;
    if (k < 256)            v = Whh[n * 256 + k];
    else if (k - 256 < IN)  v = Wih[n * IN + (k - 256)];
    Wp[idx] = (_Float16)v;
}

// ---------- main persistent kernel ----------

__global__ __launch_bounds__(512, 2) void lstm7(
    const float* __restrict__ in0,
    const _Float16* __restrict__ xf16,
    const _Float16* __restrict__ WpE,
    const _Float16* __restrict__ WpD,
    const float* __restrict__ bihE, const float* __restrict__ bhhE,
    const float* __restrict__ bihD, const float* __restrict__ bhhD,
    const float* __restrict__ dWih,
    const float* __restrict__ fcW, const float* __restrict__ fcb,
    float* __restrict__ out) {

    __shared__ f16x8 Blds[8][16][64];       // 128 KB: kt6,7 (wave-local slices)
    __shared__ _Float16 A[2][16 * 256];     //  16 KB: h tile, dbuf, swizzled
    __shared__ f16x8 xs[2][16];             // 512 B : x staging, dbuf
    __shared__ f32x4 partial[2][16][2];     //   1 KB: decoder fc partials, dbuf

    const int tid  = threadIdx.x;
    const int lane = tid & 63;
    const int wv   = tid >> 6;
    const int l15  = lane & 15;
    const int lg   = lane >> 4;
    const int b0   = blockIdx.x * 16;

    const _Float16* wpe = WpE + wv * WPW;
    const _Float16* wpd = WpD + wv * WPW;

    // encoder weights: slots 0-4 = kt0-4, slot 5 = kt8 (all VGPR); kt6,7 -> LDS
    f16x8 wr[6][8];
#pragma unroll
    for (int kt = 0; kt < 5; ++kt)
#pragma unroll
        for (int nt = 0; nt < 8; ++nt)
            wr[kt][nt] = *(const f16x8*)(wpe + (size_t)(kt * 8 + nt) * 512 + lane * 8);
#pragma unroll
    for (int nt = 0; nt < 8; ++nt)
        wr[5][nt] = *(const f16x8*)(wpe + (size_t)(8 * 8 + nt) * 512 + lane * 8);
#pragma unroll
    for (int kt = 6; kt < 8; ++kt)
#pragma unroll
        for (int nt = 0; nt < 8; ++nt)
            Blds[wv][(kt - 6) * 8 + nt][lane] = *(const f16x8*)(wpe + (size_t)(kt * 8 + nt) * 512 + lane * 8);

    float bia[8];
#pragma unroll
    for (int nt = 0; nt < 8; ++nt) {
        int n = (nt >> 1) * 256 + wv * 32 + (nt & 1) * 16 + l15;
        bia[nt] = bihE[n] + bhhE[n];
    }
    const float fcw0 = fcW[wv * 32 + l15];
    const float fcw1 = fcW[wv * 32 + 16 + l15];
    const float fcbv = fcb[0];

    // swizzled A-frag read offsets (kt 0..7)
    int aaddr[8];
#pragma unroll
    for (int kt = 0; kt < 8; ++kt)
        aaddr[kt] = l15 * 512 + ((((kt * 4 + lg) ^ (l15 & 7)) & 31) << 4);

    // zero A[0] (h0 = 0), load x0
    for (int i = tid; i < 16 * 256; i += 512) A[0][i] = (_Float16)0.0f;
    if (tid < 128)
        ((_Float16*)&xs[0][tid >> 3])[tid & 7] = xf16[(size_t)(b0 + (tid >> 3)) * 8 + (tid & 7)];

    float c_st[2][4] = {{0.f,0.f,0.f,0.f},{0.f,0.f,0.f,0.f}};

    __syncthreads();

    // ===================== encoder: 168 steps, 1 barrier each =====================
#pragma unroll 1
    for (int it = 0; it < NENC; ++it) {
        const int rb = it & 1, wbuf = rb ^ 1;
        const char* ab = (const char*)&A[0][0] + rb * 8192;
        char*       aw = (char*)&A[0][0] + wbuf * 8192;

        f32x4 acc[8];
#pragma unroll
        for (int nt = 0; nt < 8; ++nt) { f32x4 v = {bia[nt], bia[nt], bia[nt], bia[nt]}; acc[nt] = v; }

        // stream kt5 (L2-hot, constant address)
        f16x8 s5[8];
#pragma unroll
        for (int nt = 0; nt < 8; ++nt)
            s5[nt] = *(const f16x8*)(wpe + (size_t)(5 * 8 + nt) * 512 + lane * 8);

        // prefetch next x
        _Float16 xreg = (_Float16)0.0f;
        if (it < NENC - 1 && tid < 128)
            xreg = xf16[(size_t)((it + 1) * 1024 + b0 + (tid >> 3)) * 8 + (tid & 7)];

#pragma unroll
        for (int kt = 0; kt < 5; ++kt) {
            f16x8 a = *(const f16x8*)(ab + aaddr[kt]);
            mfma8(acc, a, wr[kt]);
        }
        {
            f16x8 a = *(const f16x8*)(ab + aaddr[5]);
            mfma8(acc, a, s5);
        }
#pragma unroll
        for (int kt = 6; kt < 8; ++kt) {
            f16x8 a = *(const f16x8*)(ab + aaddr[kt]);
#pragma unroll
            for (int nt = 0; nt < 8; ++nt)
                acc[nt] = mfma(a, Blds[wv][(kt - 6) * 8 + nt][lane], acc[nt]);
        }
        {
            // kt8: B-frag (wr[5]) is zero on lanes lg>0, so xs on all lanes is exact
            f16x8 a = xs[rb][l15];
            mfma8(acc, a, wr[5]);
        }

        // activation + h write (swizzled) into the OTHER buffer
#pragma unroll
        for (int half = 0; half < 2; ++half) {
#pragma unroll
            for (int r = 0; r < 4; ++r) {
                float iv = acc[0 + half][r];
                float fv = acc[2 + half][r];
                float gv = acc[4 + half][r];
                float ov = acc[6 + half][r];
                float cn = sigm(fv) * c_st[half][r] + sigm(iv) * tanh_f(gv);
                c_st[half][r] = cn;
                float hn = sigm(ov) * tanh_f(cn);
                int row  = lg * 4 + r;
                int colb = (wv * 32 + half * 16 + l15) * 2;
                *(_Float16*)(aw + row * 512 + (colb ^ ((row & 7) << 4))) = (_Float16)hn;
            }
        }
        if (it < NENC - 1 && tid < 128)
            ((_Float16*)&xs[wbuf][tid >> 3])[tid & 7] = xreg;

        __syncthreads();    // the only per-step barrier
    }

    // ---------- phase switch: decoder weights (wave-local; no barrier needed) ----------
#pragma unroll
    for (int kt = 0; kt < 5; ++kt)
#pragma unroll
        for (int nt = 0; nt < 8; ++nt)
            wr[kt][nt] = *(const f16x8*)(wpd + (size_t)(kt * 8 + nt) * 512 + lane * 8);
#pragma unroll
    for (int kt = 6; kt < 8; ++kt)
#pragma unroll
        for (int nt = 0; nt < 8; ++nt)
            Blds[wv][(kt - 6) * 8 + nt][lane] = *(const f16x8*)(wpd + (size_t)(kt * 8 + nt) * 512 + lane * 8);

    float wih_s[8];
#pragma unroll
    for (int nt = 0; nt < 8; ++nt) {
        int n = (nt >> 1) * 256 + wv * 32 + (nt & 1) * 16 + l15;
        bia[nt]   = bihD[n] + bhhD[n];
        wih_s[nt] = dWih[n];
    }
    float pred[4];
#pragma unroll
    for (int r = 0; r < 4; ++r)
        pred[r] = in0[((size_t)(b0 + lg * 4 + r) * 168 + 167) * 8 + 0];

    // ===================== decoder: 96 steps, 1 barrier each =====================
#pragma unroll 1
    for (int s = 0; s < NDEC; ++s) {
        const int it = NENC + s;
        const int rb = it & 1, wbuf = rb ^ 1;
        const char* ab = (const char*)&A[0][0] + rb * 8192;
        char*       aw = (char*)&A[0][0] + wbuf * 8192;

        if (s > 0) {
#pragma unroll
            for (int r = 0; r < 4; ++r) {
                const int row = lg * 4 + r;
                f32x4 pa = partial[rb][row][0];
                f32x4 pb = partial[rb][row][1];
                pred[r] = fcbv + (((pa[0] + pa[1]) + (pa[2] + pa[3]))
                                + ((pb[0] + pb[1]) + (pb[2] + pb[3])));
                if (wv == 0 && l15 == 0)
                    out[(size_t)(b0 + row) * 96 + (s - 1)] = pred[r];
            }
        }

        f32x4 acc[8];
#pragma unroll
        for (int nt = 0; nt < 8; ++nt) {
            f32x4 v;
#pragma unroll
            for (int r = 0; r < 4; ++r) v[r] = __builtin_fmaf(wih_s[nt], pred[r], bia[nt]);
            acc[nt] = v;
        }

        f16x8 s5[8];
#pragma unroll
        for (int nt = 0; nt < 8; ++nt)
            s5[nt] = *(const f16x8*)(wpd + (size_t)(5 * 8 + nt) * 512 + lane * 8);

#pragma unroll
        for (int kt = 0; kt < 5; ++kt) {
            f16x8 a = *(const f16x8*)(ab + aaddr[kt]);
            mfma8(acc, a, wr[kt]);
        }
        {
            f16x8 a = *(const f16x8*)(ab + aaddr[5]);
            mfma8(acc, a, s5);
        }
#pragma unroll
        for (int kt = 6; kt < 8; ++kt) {
            f16x8 a = *(const f16x8*)(ab + aaddr[kt]);
#pragma unroll
            for (int nt = 0; nt < 8; ++nt)
                acc[nt] = mfma(a, Blds[wv][(kt - 6) * 8 + nt][lane], acc[nt]);
        }
        // (no kt8: x-term folded into acc init)

        float hnv[2][4];
#pragma unroll
        for (int half = 0; half < 2; ++half) {
#pragma unroll
            for (int r = 0; r < 4; ++r) {
                float iv = acc[0 + half][r];
                float fv = acc[2 + half][r];
                float gv = acc[4 + half][r];
                float ov = acc[6 + half][r];
                float cn = sigm(fv) * c_st[half][r] + sigm(iv) * tanh_f(gv);
                c_st[half][r] = cn;
                float hn = sigm(ov) * tanh_f(cn);
                hnv[half][r] = hn;
                int row  = lg * 4 + r;
                int colb = (wv * 32 + half * 16 + l15) * 2;
                *(_Float16*)(aw + row * 512 + (colb ^ ((row & 7) << 4))) = (_Float16)hn;
            }
        }
        // fc partials for the NEXT step's pred
#pragma unroll
        for (int r = 0; r < 4; ++r) {
            float pv = hnv[0][r] * fcw0 + hnv[1][r] * fcw1;
            pv += __shfl_xor(pv, 1);
            pv += __shfl_xor(pv, 2);
            pv += __shfl_xor(pv, 4);
            pv += __shfl_xor(pv, 8);
            if (l15 == 0)
                ((float*)&partial[wbuf][lg * 4 + r][0])[wv] = pv;
        }

        __syncthreads();    // the only per-step barrier
    }

    // tail: last prediction (it=263 wrote partial[0])
    if (wv == 0 && l15 == 0) {
#pragma unroll
        for (int r = 0; r < 4; ++r) {
            const int row = lg * 4 + r;
            f32x4 pa = partial[0][row][0];
            f32x4 pb = partial[0][row][1];
            float pr = fcbv + (((pa[0] + pa[1]) + (pa[2] + pa[3]))
                             + ((pb[0] + pb[1]) + (pb[2] + pb[3])));
            out[(size_t)(b0 + row) * 96 + 95] = pr;
        }
    }
}

// ---------- launch ----------

extern "C" void kernel_launch(void* const* d_in, const int* in_sizes, int n_in,
                              void* d_out, int out_size, void* d_ws, size_t ws_size,
                              hipStream_t stream) {
    const float* inputs  = (const float*)d_in[0];
    const float* enc_Wih = (const float*)d_in[1];
    const float* enc_Whh = (const float*)d_in[2];
    const float* enc_bih = (const float*)d_in[3];
    const float* enc_bhh = (const float*)d_in[4];
    const float* dec_Wih = (const float*)d_in[5];
    const float* dec_Whh = (const float*)d_in[6];
    const float* dec_bih = (const float*)d_in[7];
    const float* dec_bhh = (const float*)d_in[8];
    const float* fc_W    = (const float*)d_in[9];
    const float* fc_b    = (const float*)d_in[10];

    char* ws = (char*)d_ws;
    _Float16* xf16 = (_Float16*)(ws);
    _Float16* WpE  = (_Float16*)(ws + 2752512);
    _Float16* WpD  = (_Float16*)(ws + 2752512 + 589824);

    k_convert_x<<<dim3(5376), dim3(256), 0, stream>>>(inputs, xf16);
    k_pack_w<<<dim3(1152), dim3(256), 0, stream>>>(enc_Whh, enc_Wih, 8, WpE);
    k_pack_w<<<dim3(1152), dim3(256), 0, stream>>>(dec_Whh, dec_Wih, 1, WpD);

    lstm7<<<dim3(64), dim3(512), 0, stream>>>(
        inputs, xf16, WpE, WpD, enc_bih, enc_bhh, dec_bih, dec_bhh,
        dec_Wih, fc_W, fc_b, (float*)d_out);
}

// Round 8
// 1657.942 us; speedup vs baseline: 2.1879x; 1.0941x over previous
//
#include <hip/hip_runtime.h>

// Seq2Seq LSTM (B=1024, T_IN=168, F_IN=8, H=256, T_OUT=96) on gfx950.
// Round 8: r7's structure with r3's register budget.
//   r6 (spill) and r7 (VGPR<->AGPR shuffle) both regressed from holding 48
//   weight frags in registers. This keeps exactly r3's 40 (kt0-4) and:
//   - kt5 streamed per step (L2-hot, 8 loads, consumed mid-step)
//   - kt6,7 LDS-resident (128 KB)
//   - kt8 streamed per step as 16-lane broadcast loads (256B/wave, issued
//     after s5 is consumed, used last; A-operand masked by lg==0)
//   - A tile double-buffered, r3's 2-bit XOR swizzle, ONE barrier/step
//   - decoder x-term rank-1 fold (dec_Wih is [1024x1]); no xs feedback,
//     no serial section, partial[] double-buffered
// 64 blocks x 512 threads; wave wv owns h-units [wv*32, +32).

typedef _Float16 f16x8 __attribute__((ext_vector_type(8)));
typedef float f32x4 __attribute__((ext_vector_type(4)));

#define WPW  36864
#define NENC 168
#define NDEC 96

__device__ __forceinline__ float sigm(float x) {
    float e = __builtin_amdgcn_exp2f(-1.4426950408889634f * x);
    return __builtin_amdgcn_rcpf(1.0f + e);
}
__device__ __forceinline__ float tanh_f(float x) {
    float e = __builtin_amdgcn_exp2f(-2.8853900817779268f * x);
    return 2.0f * __builtin_amdgcn_rcpf(1.0f + e) - 1.0f;
}
__device__ __forceinline__ f32x4 mfma(f16x8 a, f16x8 b, f32x4 c) {
    return __builtin_amdgcn_mfma_f32_16x16x32_f16(a, b, c, 0, 0, 0);
}
__device__ __forceinline__ void mfma8(f32x4 acc[8], f16x8 a, const f16x8 b[8]) {
#pragma unroll
    for (int nt = 0; nt < 8; ++nt) acc[nt] = mfma(a, b[nt], acc[nt]);
}

// ---------- setup kernels (unchanged) ----------

__global__ void k_convert_x(const float* __restrict__ in, _Float16* __restrict__ xf16) {
    int idx = blockIdx.x * 256 + threadIdx.x;     // (t*1024+b)*8+f
    if (idx >= 168 * 1024 * 8) return;
    int f = idx & 7;
    int b = (idx >> 3) & 1023;
    int t = idx >> 13;
    xf16[idx] = (_Float16)in[(b * 168 + t) * 8 + f];
}

__global__ void k_pack_w(const float* __restrict__ Whh, const float* __restrict__ Wih,
                         int IN, _Float16* __restrict__ Wp) {
    int idx = blockIdx.x * 256 + threadIdx.x;
    if (idx >= 294912) return;
    int j    = idx & 7;
    int lane = (idx >> 3) & 63;
    int nt   = (idx >> 9) & 7;
    int kt   = (idx >> 12) % 9;
    int wv   = idx / 36864;
    int n = (nt >> 1) * 256 + wv * 32 + (nt & 1) * 16 + (lane & 15);
    int k = kt * 32 + (lane >> 4) * 8 + j;
    float v = 0.0f;
    if (k < 256)            v = Whh[n * 256 + k];
    else if (k - 256 < IN)  v = Wih[n * IN + (k - 256)];
    Wp[idx] = (_Float16)v;
}

// ---------- main persistent kernel ----------

__global__ __launch_bounds__(512, 2) void lstm8(
    const float* __restrict__ in0,
    const _Float16* __restrict__ xf16,
    const _Float16* __restrict__ WpE,
    const _Float16* __restrict__ WpD,
    const float* __restrict__ bihE, const float* __restrict__ bhhE,
    const float* __restrict__ bihD, const float* __restrict__ bhhD,
    const float* __restrict__ dWih,
    const float* __restrict__ fcW, const float* __restrict__ fcb,
    float* __restrict__ out) {

    __shared__ f16x8 Blds[8][16][64];       // 128 KB: kt6,7 (wave-local slices)
    __shared__ _Float16 A[2][16 * 256];     //  16 KB: h tile, dbuf, 2-bit swizzle
    __shared__ f16x8 xs[2][16];             // 512 B : x staging, dbuf
    __shared__ f32x4 partial[2][16][2];     //   1 KB: decoder fc partials, dbuf

    const int tid  = threadIdx.x;
    const int lane = tid & 63;
    const int wv   = tid >> 6;
    const int l15  = lane & 15;
    const int lg   = lane >> 4;
    const int b0   = blockIdx.x * 16;

    const _Float16* wpe = WpE + wv * WPW;
    const _Float16* wpd = WpD + wv * WPW;
    const _Float16* wp8e = wpe + 64 * 512;  // kt8 region (encoder)

    // encoder weights: kt0-4 -> VGPR (40 frags, r3's proven budget); kt6,7 -> LDS
    f16x8 wr[5][8];
#pragma unroll
    for (int kt = 0; kt < 5; ++kt)
#pragma unroll
        for (int nt = 0; nt < 8; ++nt)
            wr[kt][nt] = *(const f16x8*)(wpe + (size_t)(kt * 8 + nt) * 512 + lane * 8);
#pragma unroll
    for (int kt = 6; kt < 8; ++kt)
#pragma unroll
        for (int nt = 0; nt < 8; ++nt)
            Blds[wv][(kt - 6) * 8 + nt][lane] = *(const f16x8*)(wpe + (size_t)(kt * 8 + nt) * 512 + lane * 8);

    float bia[8];
#pragma unroll
    for (int nt = 0; nt < 8; ++nt) {
        int n = (nt >> 1) * 256 + wv * 32 + (nt & 1) * 16 + l15;
        bia[nt] = bihE[n] + bhhE[n];
    }
    const float fcw0 = fcW[wv * 32 + l15];
    const float fcw1 = fcW[wv * 32 + 16 + l15];
    const float fcbv = fcb[0];

    // r3's swizzled A-frag read offsets: linear kt*64, XOR confined to bits[5:4]
    int aaddr[8];
#pragma unroll
    for (int kt = 0; kt < 8; ++kt)
        aaddr[kt] = l15 * 512 + kt * 64 + ((lg * 16) ^ ((l15 & 3) << 4));

    // zero A[0] (h0 = 0; A[1] fully overwritten at it=0), load x0
    for (int i = tid; i < 16 * 256; i += 512) A[0][i] = (_Float16)0.0f;
    if (tid < 128)
        ((_Float16*)&xs[0][tid >> 3])[tid & 7] = xf16[(size_t)(b0 + (tid >> 3)) * 8 + (tid & 7)];

    float c_st[2][4] = {{0.f,0.f,0.f,0.f},{0.f,0.f,0.f,0.f}};

    __syncthreads();

    // ===================== encoder: 168 steps, 1 barrier each =====================
#pragma unroll 1
    for (int it = 0; it < NENC; ++it) {
        const int rb = it & 1, wbuf = rb ^ 1;
        const char* ab = (const char*)&A[0][0] + rb * 8192;
        char*       aw = (char*)&A[0][0] + wbuf * 8192;

        f32x4 acc[8];
#pragma unroll
        for (int nt = 0; nt < 8; ++nt) { f32x4 v = {bia[nt], bia[nt], bia[nt], bia[nt]}; acc[nt] = v; }

        // stream kt5 (L2-hot, constant address) + x prefetch
        f16x8 s5[8];
#pragma unroll
        for (int nt = 0; nt < 8; ++nt)
            s5[nt] = *(const f16x8*)(wpe + (size_t)(5 * 8 + nt) * 512 + lane * 8);
        _Float16 xreg = (_Float16)0.0f;
        if (it < NENC - 1 && tid < 128)
            xreg = xf16[(size_t)((it + 1) * 1024 + b0 + (tid >> 3)) * 8 + (tid & 7)];

        // kt0-4 (register weights)
#pragma unroll
        for (int kt = 0; kt < 5; ++kt) {
            f16x8 a = *(const f16x8*)(ab + aaddr[kt]);
            mfma8(acc, a, wr[kt]);
        }
        // kt5 (streamed) — s5 dies here
        {
            f16x8 a = *(const f16x8*)(ab + aaddr[5]);
            mfma8(acc, a, s5);
        }
        __builtin_amdgcn_sched_barrier(0);
        // kt8 broadcast loads issue now (live range doesn't overlap s5)
        f16x8 k8b[8];
#pragma unroll
        for (int nt = 0; nt < 8; ++nt)
            k8b[nt] = *(const f16x8*)(wp8e + (size_t)nt * 512 + l15 * 8);
        // kt6,7 (LDS weights) — covers k8b latency
#pragma unroll
        for (int kt = 6; kt < 8; ++kt) {
            f16x8 a = *(const f16x8*)(ab + aaddr[kt]);
#pragma unroll
            for (int nt = 0; nt < 8; ++nt)
                acc[nt] = mfma(a, Blds[wv][(kt - 6) * 8 + nt][lane], acc[nt]);
        }
        // kt8: mask the A-operand (k8b rows are only valid for lg==0 lanes)
        {
            f16x8 a = xs[rb][l15];
            _Float16 m = (_Float16)(lg == 0 ? 1.0f : 0.0f);
            a = a * m;
            mfma8(acc, a, k8b);
        }

        // activation + h write (swizzled) into the other buffer
#pragma unroll
        for (int half = 0; half < 2; ++half) {
#pragma unroll
            for (int r = 0; r < 4; ++r) {
                float iv = acc[0 + half][r];
                float fv = acc[2 + half][r];
                float gv = acc[4 + half][r];
                float ov = acc[6 + half][r];
                float cn = sigm(fv) * c_st[half][r] + sigm(iv) * tanh_f(gv);
                c_st[half][r] = cn;
                float hn = sigm(ov) * tanh_f(cn);
                int row  = lg * 4 + r;
                int colb = (wv * 32 + half * 16 + l15) * 2;
                *(_Float16*)(aw + row * 512 + (colb ^ ((r & 3) << 4))) = (_Float16)hn;
            }
        }
        if (it < NENC - 1 && tid < 128)
            ((_Float16*)&xs[wbuf][tid >> 3])[tid & 7] = xreg;

        __syncthreads();    // the only per-step barrier
    }

    // ---------- phase switch: decoder weights (wave-local; no barrier) ----------
#pragma unroll
    for (int kt = 0; kt < 5; ++kt)
#pragma unroll
        for (int nt = 0; nt < 8; ++nt)
            wr[kt][nt] = *(const f16x8*)(wpd + (size_t)(kt * 8 + nt) * 512 + lane * 8);
#pragma unroll
    for (int kt = 6; kt < 8; ++kt)
#pragma unroll
        for (int nt = 0; nt < 8; ++nt)
            Blds[wv][(kt - 6) * 8 + nt][lane] = *(const f16x8*)(wpd + (size_t)(kt * 8 + nt) * 512 + lane * 8);

    float wih_s[8];
#pragma unroll
    for (int nt = 0; nt < 8; ++nt) {
        int n = (nt >> 1) * 256 + wv * 32 + (nt & 1) * 16 + l15;
        bia[nt]   = bihD[n] + bhhD[n];
        wih_s[nt] = dWih[n];
    }
    float pred[4];
#pragma unroll
    for (int r = 0; r < 4; ++r)
        pred[r] = in0[((size_t)(b0 + lg * 4 + r) * 168 + 167) * 8 + 0];

    // ===================== decoder: 96 steps, 1 barrier each =====================
#pragma unroll 1
    for (int s = 0; s < NDEC; ++s) {
        const int it = NENC + s;
        const int rb = it & 1, wbuf = rb ^ 1;
        const char* ab = (const char*)&A[0][0] + rb * 8192;
        char*       aw = (char*)&A[0][0] + wbuf * 8192;

        if (s > 0) {
#pragma unroll
            for (int r = 0; r < 4; ++r) {
                const int row = lg * 4 + r;
                f32x4 pa = partial[rb][row][0];
                f32x4 pb = partial[rb][row][1];
                pred[r] = fcbv + (((pa[0] + pa[1]) + (pa[2] + pa[3]))
                                + ((pb[0] + pb[1]) + (pb[2] + pb[3])));
                if (wv == 0 && l15 == 0)
                    out[(size_t)(b0 + row) * 96 + (s - 1)] = pred[r];
            }
        }

        f32x4 acc[8];
#pragma unroll
        for (int nt = 0; nt < 8; ++nt) {
            f32x4 v;
#pragma unroll
            for (int r = 0; r < 4; ++r) v[r] = __builtin_fmaf(wih_s[nt], pred[r], bia[nt]);
            acc[nt] = v;
        }

        f16x8 s5[8];
#pragma unroll
        for (int nt = 0; nt < 8; ++nt)
            s5[nt] = *(const f16x8*)(wpd + (size_t)(5 * 8 + nt) * 512 + lane * 8);

#pragma unroll
        for (int kt = 0; kt < 5; ++kt) {
            f16x8 a = *(const f16x8*)(ab + aaddr[kt]);
            mfma8(acc, a, wr[kt]);
        }
        {
            f16x8 a = *(const f16x8*)(ab + aaddr[5]);
            mfma8(acc, a, s5);
        }
#pragma unroll
        for (int kt = 6; kt < 8; ++kt) {
            f16x8 a = *(const f16x8*)(ab + aaddr[kt]);
#pragma unroll
            for (int nt = 0; nt < 8; ++nt)
                acc[nt] = mfma(a, Blds[wv][(kt - 6) * 8 + nt][lane], acc[nt]);
        }
        // (no kt8: x-term folded into acc init)

        float hnv[2][4];
#pragma unroll
        for (int half = 0; half < 2; ++half) {
#pragma unroll
            for (int r = 0; r < 4; ++r) {
                float iv = acc[0 + half][r];
                float fv = acc[2 + half][r];
                float gv = acc[4 + half][r];
                float ov = acc[6 + half][r];
                float cn = sigm(fv) * c_st[half][r] + sigm(iv) * tanh_f(gv);
                c_st[half][r] = cn;
                float hn = sigm(ov) * tanh_f(cn);
                hnv[half][r] = hn;
                int row  = lg * 4 + r;
                int colb = (wv * 32 + half * 16 + l15) * 2;
                *(_Float16*)(aw + row * 512 + (colb ^ ((r & 3) << 4))) = (_Float16)hn;
            }
        }
        // fc partials for the NEXT step's pred
#pragma unroll
        for (int r = 0; r < 4; ++r) {
            float pv = hnv[0][r] * fcw0 + hnv[1][r] * fcw1;
            pv += __shfl_xor(pv, 1);
            pv += __shfl_xor(pv, 2);
            pv += __shfl_xor(pv, 4);
            pv += __shfl_xor(pv, 8);
            if (l15 == 0)
                ((float*)&partial[wbuf][lg * 4 + r][0])[wv] = pv;
        }

        __syncthreads();    // the only per-step barrier
    }

    // tail: last prediction (it=263: rb=1, wrote partial[0])
    if (wv == 0 && l15 == 0) {
#pragma unroll
        for (int r = 0; r < 4; ++r) {
            const int row = lg * 4 + r;
            f32x4 pa = partial[0][row][0];
            f32x4 pb = partial[0][row][1];
            float pr = fcbv + (((pa[0] + pa[1]) + (pa[2] + pa[3]))
                             + ((pb[0] + pb[1]) + (pb[2] + pb[3])));
            out[(size_t)(b0 + row) * 96 + 95] = pr;
        }
    }
}

// ---------- launch ----------

extern "C" void kernel_launch(void* const* d_in, const int* in_sizes, int n_in,
                              void* d_out, int out_size, void* d_ws, size_t ws_size,
                              hipStream_t stream) {
    const float* inputs  = (const float*)d_in[0];
    const float* enc_Wih = (const float*)d_in[1];
    const float* enc_Whh = (const float*)d_in[2];
    const float* enc_bih = (const float*)d_in[3];
    const float* enc_bhh = (const float*)d_in[4];
    const float* dec_Wih = (const float*)d_in[5];
    const float* dec_Whh = (const float*)d_in[6];
    const float* dec_bih = (const float*)d_in[7];
    const float* dec_bhh = (const float*)d_in[8];
    const float* fc_W    = (const float*)d_in[9];
    const float* fc_b    = (const float*)d_in[10];

    char* ws = (char*)d_ws;
    _Float16* xf16 = (_Float16*)(ws);
    _Float16* WpE  = (_Float16*)(ws + 2752512);
    _Float16* WpD  = (_Float16*)(ws + 2752512 + 589824);

    k_convert_x<<<dim3(5376), dim3(256), 0, stream>>>(inputs, xf16);
    k_pack_w<<<dim3(1152), dim3(256), 0, stream>>>(enc_Whh, enc_Wih, 8, WpE);
    k_pack_w<<<dim3(1152), dim3(256), 0, stream>>>(dec_Whh, dec_Wih, 1, WpD);

    lstm8<<<dim3(64), dim3(512), 0, stream>>>(
        inputs, xf16, WpE, WpD, enc_bih, enc_bhh, dec_bih, dec_bhh,
        dec_Wih, fc_W, fc_b, (float*)d_out);
}